// Round 8
// baseline (207.343 us; speedup 1.0000x reference)
//
#include <hip/hip_runtime.h>
#include <stdint.h>

#define NIMG 8
#define NCLS 80
#define HF 100
#define WF 152
#define NPTS (HF*WF)          // 15200
#define NPC (NPTS*NCLS)       // 1216000
#define NF4 (NPC/4)           // 304000 float4 groups per image
#define TOPK 1000
#define NSH 8                 // candidate shards per image
#define SHCAP 512             // slots per shard (expected ~300, cap = +12 sigma)
#define SORTN 4096            // max total candidates = NSH*SHCAP
#define LBUF 1024             // per-block LDS candidate buffer
#define POSTK 100
#define HBLK 297              // ceil(NF4/1024): 256 thr x 4 float4 groups = 4096 elems/block
#define RBLK (SORTN/256)      // 16 rank blocks per image
#define SCHUNK 32             // sample chunks per image
#define SSTRIDE 9500          // groups between chunk starts (32*9500+255 < 304000)
#define SM_T 65               // sample-suffix target: ~65/0.02695 = 2400 expected true count

// ---- workspace layout (bytes) ----
static constexpr size_t B_CNT  = 0;                                    // u32 [8][NSH]
static constexpr size_t B_META = B_CNT + (size_t)NIMG*NSH*4;           // u32 [8][4] {-, T_raw, -, -}
static constexpr size_t B_SKEY = (B_META + NIMG*4*4 + 7) & ~(size_t)7; // u64 [8][1024]
static constexpr size_t B_CTRS = (B_SKEY + (size_t)NIMG*1024*8 + 15) & ~(size_t)15; // f32 [8][15200]
static constexpr size_t B_CAND = (B_CTRS + (size_t)NIMG*NPTS*4 + 15) & ~(size_t)15; // u64 [8][NSH][SHCAP]
static constexpr size_t B_BOX  = B_CAND + (size_t)NIMG*NSH*SHCAP*8;    // f32 [8][TOPK][4]
static constexpr size_t B_OBOX = B_BOX + (size_t)NIMG*TOPK*16;         // f32 [8][TOPK][4]
static constexpr size_t B_SC   = B_OBOX + (size_t)NIMG*TOPK*16;        // f32 [8][TOPK]
static constexpr size_t B_VAL  = B_SC + (size_t)NIMG*TOPK*4;           // u32 [8][TOPK]
static constexpr size_t B_LAB  = B_VAL + (size_t)NIMG*TOPK*4;          // u32 [8][TOPK]
static constexpr size_t B_KEEP = B_LAB + (size_t)NIMG*TOPK*4;          // u32 [8][TOPK]
#define ZWORDS (NIMG*NSH + NIMG*4)   // cnt + meta u32 words (contiguous)

__device__ __forceinline__ float sigm(float x){ return 1.0f / (1.0f + expf(-x)); }

// sigmoid(centerness) precompute + zero cnt/meta/skey (replaces hipMemsetAsync)
__global__ void __launch_bounds__(256)
k_ctrsig(const float* __restrict__ ctr, float* __restrict__ ctr_sig,
         uint32_t* __restrict__ zr, uint64_t* __restrict__ skey){
  const int gid = blockIdx.x * 256 + threadIdx.x;
  const int nthr = 119 * 256;
  if (gid < NIMG*NPTS/4){
    float4 v = ((const float4*)ctr)[gid];
    float4 o;
    o.x = sigm(v.x); o.y = sigm(v.y); o.z = sigm(v.z); o.w = sigm(v.w);
    ((float4*)ctr_sig)[gid] = o;
  }
  for (int i = gid; i < ZWORDS; i += nthr) zr[i] = 0u;           // cnt + meta
  for (int i = gid; i < NIMG*1024; i += nthr) skey[i] = 0ull;    // skey
}

// sample ~2.7% of elements, build 4096-bin hist, pick speculative threshold T_raw:
// largest bin with sample-suffix >= SM_T  =>  expected true count(>=T) ~ 2400.
// T_raw is a PERFORMANCE HINT ONLY: k_fallback guarantees exactness for any T_raw.
__global__ void __launch_bounds__(256)
k_sample(const float* __restrict__ box_cls, const float* __restrict__ ctr_sig,
         uint32_t* __restrict__ meta){
  __shared__ uint32_t h[4096];
  __shared__ uint32_t psum[256], suff[256];
  const int n = blockIdx.x;
  const int t = threadIdx.x;
  for (int i = t; i < 4096; i += 256) h[i] = 0;
  __syncthreads();
  const float4* cls4 = (const float4*)(box_cls + (size_t)n * NPC);
  const float* cs = ctr_sig + (size_t)n * NPTS;
  for (int c0 = 0; c0 < SCHUNK; c0 += 4){
    float4 a[4], b[4];
    #pragma unroll
    for (int k = 0; k < 4; ++k){
      int g = (c0 + k) * SSTRIDE + t;
      a[k] = cls4[g];
      uint32_t p0 = ((uint32_t)(g << 2)) % (uint32_t)NPTS;
      b[k] = *(const float4*)(cs + p0);
    }
    __builtin_amdgcn_sched_barrier(0);
    #pragma unroll
    for (int k = 0; k < 4; ++k){
      float sv[4] = {a[k].x, a[k].y, a[k].z, a[k].w};
      float cv[4] = {b[k].x, b[k].y, b[k].z, b[k].w};
      #pragma unroll
      for (int j = 0; j < 4; ++j){
        float s = sigm(sv[j]);
        if (s > 0.05f){
          float sc = s * cv[j];
          if (sc > 0.0f) atomicAdd(&h[__float_as_uint(sc) >> 18], 1u);
        }
      }
    }
  }
  __syncthreads();
  uint32_t s = 0;
  #pragma unroll
  for (int i = 0; i < 16; ++i) s += h[t * 16 + i];
  psum[t] = s;
  __syncthreads();
  if (t == 0){
    uint32_t acc = 0;
    for (int seg = 255; seg >= 0; --seg){ suff[seg] = acc; acc += psum[seg]; }
  }
  __syncthreads();
  if (suff[t] < SM_T && suff[t] + psum[t] >= SM_T){
    uint32_t acc = suff[t];
    for (int b = t * 16 + 15; b >= t * 16; --b){
      uint32_t hb = h[b];
      if (acc + hb >= SM_T){
        meta[n * 4 + 1] = ((uint32_t)b) << 18;   // raw-bits threshold
        break;
      }
      acc += hb;
    }
  }
}

// THE single full pass: compute scores, collect bits >= T_raw into sharded buffers.
// No histogram, no global merge, no second pass (replaces old hist+scan+collect).
__global__ void __launch_bounds__(256)
k_main(const float* __restrict__ box_cls, const float* __restrict__ ctr_sig,
       const uint32_t* __restrict__ meta,
       uint32_t* __restrict__ cnt, uint64_t* __restrict__ cand){
  __shared__ uint64_t buf[LBUF];
  __shared__ uint32_t lcnt;
  __shared__ uint32_t gbase;
  const int n = blockIdx.y;
  const uint32_t Traw = meta[n * 4 + 1];
  if (threadIdx.x == 0) lcnt = 0;
  __syncthreads();
  const float4* cls4 = (const float4*)(box_cls + (size_t)n * NPC);
  const float* cs = ctr_sig + (size_t)n * NPTS;
  const int base4 = blockIdx.x * 1024 + threadIdx.x;
  float4 a[4], b[4];
  int p0a[4], ca[4];
  bool ok[4];
  #pragma unroll
  for (int k = 0; k < 4; ++k){
    int i4 = base4 + k * 256;
    ok[k] = (i4 < NF4);
    if (ok[k]){
      a[k] = cls4[i4];
      uint32_t e0 = (uint32_t)(i4 << 2);
      uint32_t c = e0 / (uint32_t)NPTS;      // constant within a 4-aligned group
      uint32_t p0 = e0 - c * (uint32_t)NPTS;
      ca[k] = (int)c; p0a[k] = (int)p0;
      b[k] = *(const float4*)(cs + p0);
    }
  }
  __builtin_amdgcn_sched_barrier(0);         // keep all 8 loads issued up-front (MLP)
  #pragma unroll
  for (int k = 0; k < 4; ++k){
    if (!ok[k]) continue;
    float sv[4] = {a[k].x, a[k].y, a[k].z, a[k].w};
    float cv[4] = {b[k].x, b[k].y, b[k].z, b[k].w};
    #pragma unroll
    for (int j = 0; j < 4; ++j){
      float s = sigm(sv[j]);
      if (s > 0.05f){
        float sc = s * cv[j];
        if (sc > 0.0f){
          uint32_t bits = __float_as_uint(sc);
          if (bits >= Traw){
            uint32_t f = (uint32_t)(p0a[k] + j) * NCLS + (uint32_t)ca[k]; // ref flat idx
            uint32_t pos = atomicAdd(&lcnt, 1u);
            if (pos < LBUF)
              buf[pos] = ((uint64_t)bits << 32) | (uint64_t)(0xFFFFFFFFu - f);
          }
        }
      }
    }
  }
  __syncthreads();
  uint32_t c = lcnt; if (c > LBUF) c = LBUF;
  const int sh = blockIdx.x & (NSH - 1);
  if (threadIdx.x == 0 && c) gbase = atomicAdd(&cnt[n * NSH + sh], c);  // 1 atomic/block
  __syncthreads();
  for (uint32_t i = threadIdx.x; i < c; i += 256){
    uint32_t p = gbase + i;
    if (p < SHCAP) cand[(((size_t)n * NSH + sh) << 9) + p] = buf[i];
  }
}

// Exactness guard (always launched; no-op when speculation succeeded).
// ok = (no shard overflow) AND (total >= TOPK OR T_raw == 0).
// Otherwise: exact in-block hist + scan + re-collect (slow; statistically never hit).
__global__ void __launch_bounds__(1024)
k_fallback(const float* __restrict__ box_cls, const float* __restrict__ ctr_sig,
           const uint32_t* __restrict__ meta,
           uint32_t* __restrict__ cnt, uint64_t* __restrict__ cand){
  __shared__ uint32_t h[4096];
  __shared__ uint32_t psum[256], suff[256];
  __shared__ uint32_t ok_s, T14_s, ctr_s;
  const int n = blockIdx.x;
  const int t = threadIdx.x;
  if (t == 0){
    uint32_t total = 0, bad = 0;
    for (int s = 0; s < NSH; ++s){
      uint32_t c = cnt[n * NSH + s];
      total += c; bad |= (c > SHCAP) ? 1u : 0u;
    }
    uint32_t Traw = meta[n * 4 + 1];
    ok_s = (!bad && (total >= TOPK || Traw == 0u)) ? 1u : 0u;
    T14_s = 0; ctr_s = 0;
  }
  __syncthreads();
  if (ok_s) return;
  // ---- slow exact path ----
  for (int i = t; i < 4096; i += 1024) h[i] = 0;
  __syncthreads();
  const float* cls = box_cls + (size_t)n * NPC;
  const float* cs = ctr_sig + (size_t)n * NPTS;
  for (int e = t; e < NPC; e += 1024){
    int c = e / NPTS, p = e - c * NPTS;
    float s = sigm(cls[e]);
    if (s > 0.05f){
      float sc = s * cs[p];
      if (sc > 0.0f) atomicAdd(&h[__float_as_uint(sc) >> 18], 1u);
    }
  }
  __syncthreads();
  if (t < 256){
    uint32_t s = 0;
    #pragma unroll
    for (int i = 0; i < 16; ++i) s += h[t * 16 + i];
    psum[t] = s;
  }
  __syncthreads();
  if (t == 0){
    uint32_t acc = 0;
    for (int seg = 255; seg >= 0; --seg){ suff[seg] = acc; acc += psum[seg]; }
  }
  __syncthreads();
  if (t < 256 && suff[t] < TOPK && suff[t] + psum[t] >= TOPK){
    uint32_t acc = suff[t];
    for (int b = t * 16 + 15; b >= t * 16; --b){
      uint32_t hb = h[b];
      if (acc + hb >= TOPK){ T14_s = (uint32_t)b; break; }
      acc += hb;
    }
  }
  __syncthreads();
  const uint32_t Traw2 = T14_s << 18;        // 0 => collect all positive candidates
  if (t < NSH) cnt[n * NSH + t] = 0;
  __syncthreads();
  for (int e = t; e < NPC; e += 1024){
    int c = e / NPTS, p = e - c * NPTS;
    float s = sigm(cls[e]);
    if (s > 0.05f){
      float sc = s * cs[p];
      if (sc > 0.0f){
        uint32_t bits = __float_as_uint(sc);
        if (bits >= Traw2){
          uint32_t f = (uint32_t)p * NCLS + (uint32_t)c;
          uint32_t pos = atomicAdd(&ctr_s, 1u);
          if (pos < SORTN)
            cand[((size_t)n * NSH << 9) + pos] = ((uint64_t)bits << 32) | (uint64_t)(0xFFFFFFFFu - f);
        }
      }
    }
  }
  __syncthreads();
  if (t < NSH){
    uint32_t total = ctr_s; if (total > SORTN) total = SORTN;
    int lo = t * SHCAP;
    cnt[n * NSH + t] = ((int)total > lo) ? ((total - lo > SHCAP) ? SHCAP : total - lo) : 0u;
  }
}

// rank-based selection: rank(x) = #{y: key_y > key_x} is x's exact sorted position
// (keys unique: index embedded). Barrier-free LDS broadcast scan, 16 blocks/image.
__global__ void __launch_bounds__(256)
k_rank(const uint32_t* __restrict__ cnt, const uint64_t* __restrict__ cand,
       uint64_t* __restrict__ skey){
  __shared__ alignas(16) uint64_t keys[SORTN + 4];
  __shared__ uint32_t cs_s[NSH], pre_s[NSH + 1];
  const int n = blockIdx.y;
  const int t = threadIdx.x;
  if (t == 0){
    uint32_t acc = 0;
    for (int s = 0; s < NSH; ++s){
      uint32_t c = cnt[n * NSH + s]; if (c > SHCAP) c = SHCAP;
      cs_s[s] = c; pre_s[s] = acc; acc += c;
    }
    pre_s[NSH] = acc;
  }
  __syncthreads();
  const int total = (int)pre_s[NSH];
  const int base = blockIdx.x * 256;
  if (base >= total) return;                 // block-uniform early exit
  for (int i = t; i < SORTN; i += 256){
    int s = i >> 9, j = i & (SHCAP - 1);
    if ((uint32_t)j < cs_s[s])
      keys[pre_s[s] + j] = cand[(((size_t)n * NSH + s) << 9) + j];
  }
  if (t < 4) keys[total + t] = 0ull;         // pad for unroll-4 (0 never outranks)
  __syncthreads();
  const int g = base + t;
  const uint64_t my = (g < total) ? keys[g] : 0ull;
  uint32_t rank = 0;
  const int tot4 = (total + 3) & ~3;
  for (int i = 0; i < tot4; i += 4){         // same-address broadcast reads: conflict-free
    rank += (keys[i]     > my) ? 1u : 0u;
    rank += (keys[i + 1] > my) ? 1u : 0u;
    rank += (keys[i + 2] > my) ? 1u : 0u;
    rank += (keys[i + 3] > my) ? 1u : 0u;
  }
  if (g < total && rank < TOPK)
    skey[(size_t)n * 1024 + rank] = my;      // ranks in [0,total) are a permutation
}

// decode boxes for the 1000 rank-ordered keys (verified R5 kernel)
__global__ void __launch_bounds__(1024)
k_decode(const uint64_t* __restrict__ skey,
         const float* __restrict__ locations, const float* __restrict__ box_reg,
         const float* __restrict__ im_info,
         float* __restrict__ boxw, float* __restrict__ oboxw, float* __restrict__ scw,
         uint32_t* __restrict__ valw, uint32_t* __restrict__ labw){
  const int n = blockIdx.x;
  const int t = threadIdx.x;
  if (t < TOPK){
    uint64_t kk = skey[(size_t)n * 1024 + t];
    uint32_t bits = (uint32_t)(kk >> 32);
    uint32_t fi = 0xFFFFFFFFu - (uint32_t)(kk & 0xFFFFFFFFull);
    float v = __uint_as_float(bits);
    int loc = 0, ci = 0;
    if (v > 0.0f){ loc = (int)(fi / NCLS); ci = (int)(fi - (uint32_t)loc * NCLS); }
    float px = locations[2 * loc], py = locations[2 * loc + 1];
    const float* rg = box_reg + (size_t)n * 4 * NPTS;
    float rl = rg[loc], rt = rg[NPTS + loc], rr = rg[2 * NPTS + loc], rb = rg[3 * NPTS + loc];
    float h_im = im_info[n * 2 + 0], w_im = im_info[n * 2 + 1];
    float x1 = fminf(fmaxf(px - rl, 0.0f), w_im - 1.0f);
    float y1 = fminf(fmaxf(py - rt, 0.0f), h_im - 1.0f);
    float x2 = fminf(fmaxf(px + rr, 0.0f), w_im - 1.0f);
    float y2 = fminf(fmaxf(py + rb, 0.0f), h_im - 1.0f);
    bool valid = (v > 0.0f) && (__fsub_rn(x2, x1) >= 0.0f) && (__fsub_rn(y2, y1) >= 0.0f);
    float scv = valid ? v : 0.0f;
    float lab = (float)(ci + 1);
    float off = __fmul_rn(lab, 100000.0f);   // CLASS_OFFSET, mul then add (no fma) like ref
    size_t b4 = ((size_t)n * TOPK + t) * 4;
    boxw[b4 + 0] = x1; boxw[b4 + 1] = y1; boxw[b4 + 2] = x2; boxw[b4 + 3] = y2;
    oboxw[b4 + 0] = __fadd_rn(x1, off); oboxw[b4 + 1] = __fadd_rn(y1, off);
    oboxw[b4 + 2] = __fadd_rn(x2, off); oboxw[b4 + 3] = __fadd_rn(y2, off);
    size_t b1 = (size_t)n * TOPK + t;
    scw[b1] = scv; valw[b1] = valid ? 1u : 0u; labw[b1] = (uint32_t)(ci + 1);
  }
}

// greedy NMS per (image,class), ballot-built class list (verified R5 kernel)
__global__ void __launch_bounds__(64)
k_nms(const uint32_t* __restrict__ labw, const float* __restrict__ oboxw,
      const uint32_t* __restrict__ valw, uint32_t* __restrict__ keepw){
  const int n = blockIdx.y;
  const int c = blockIdx.x;                  // 0-based; label = c+1
  const int L = threadIdx.x;
  __shared__ uint16_t lst_s[TOPK];
  const uint32_t target = (uint32_t)(c + 1);
  uint32_t kcnt = 0;
  for (int i0 = 0; i0 < TOPK; i0 += 64){
    int slot = i0 + L;
    uint32_t lab = (slot < TOPK) ? labw[n * TOPK + slot] : 0u;
    bool m = (lab == target);
    uint64_t mask = __ballot(m);
    uint32_t pre = (uint32_t)__popcll(mask & ((1ull << L) - 1ull));
    if (m) lst_s[kcnt + pre] = (uint16_t)slot;
    kcnt += (uint32_t)__popcll(mask);        // uniform across lanes
  }
  __syncthreads();
  if (kcnt == 0) return;
  if (kcnt <= 64){
    int gi = 0, kp = 0;
    float b0 = 0, b1 = 0, b2 = 0, b3 = 0, ar = 0;
    if (L < (int)kcnt){
      gi = (int)lst_s[L];
      size_t a4 = ((size_t)n * TOPK + gi) * 4;
      b0 = oboxw[a4 + 0]; b1 = oboxw[a4 + 1]; b2 = oboxw[a4 + 2]; b3 = oboxw[a4 + 3];
      kp = (valw[n * TOPK + gi] != 0) ? 1 : 0;
      ar = __fmul_rn(fmaxf(__fsub_rn(b2, b0), 0.0f), fmaxf(__fsub_rn(b3, b1), 0.0f));
    }
    for (int i = 0; i + 1 < (int)kcnt; ++i){
      int alive = __shfl(kp, i);
      float xi0 = __shfl(b0, i), xi1 = __shfl(b1, i), xi2 = __shfl(b2, i), xi3 = __shfl(b3, i);
      float ai = __shfl(ar, i);
      if (alive && L > i && kp){
        float ltx = fmaxf(xi0, b0), lty = fmaxf(xi1, b1);
        float rbx = fminf(xi2, b2), rby = fminf(xi3, b3);
        float w = fmaxf(__fsub_rn(rbx, ltx), 0.0f);
        float h = fmaxf(__fsub_rn(rby, lty), 0.0f);
        float inter = __fmul_rn(w, h);
        float den = __fadd_rn(__fsub_rn(__fadd_rn(ai, ar), inter), 1e-9f);
        if (inter / den > 0.6f) kp = 0;
      }
    }
    if (L < (int)kcnt) keepw[n * TOPK + gi] = (uint32_t)kp;
  } else if (L == 0){
    // slow path (kcnt > 64): sequential, correctness-only (statistically never hit)
    for (uint32_t i = 0; i < kcnt; ++i){
      int gi = (int)lst_s[i];
      keepw[n * TOPK + gi] = valw[n * TOPK + gi];
    }
    for (uint32_t i = 0; i < kcnt; ++i){
      int gi = (int)lst_s[i];
      if (!keepw[n * TOPK + gi]) continue;
      size_t a4 = ((size_t)n * TOPK + gi) * 4;
      float x0 = oboxw[a4], x1 = oboxw[a4 + 1], x2 = oboxw[a4 + 2], x3 = oboxw[a4 + 3];
      float ai = __fmul_rn(fmaxf(__fsub_rn(x2, x0), 0.0f), fmaxf(__fsub_rn(x3, x1), 0.0f));
      for (uint32_t j = i + 1; j < kcnt; ++j){
        int gj = (int)lst_s[j];
        if (!keepw[n * TOPK + gj]) continue;
        size_t c4 = ((size_t)n * TOPK + gj) * 4;
        float y0 = oboxw[c4], y1 = oboxw[c4 + 1], y2 = oboxw[c4 + 2], y3 = oboxw[c4 + 3];
        float aj = __fmul_rn(fmaxf(__fsub_rn(y2, y0), 0.0f), fmaxf(__fsub_rn(y3, y1), 0.0f));
        float ltx = fmaxf(x0, y0), lty = fmaxf(x1, y1);
        float rbx = fminf(x2, y2), rby = fminf(x3, y3);
        float w = fmaxf(__fsub_rn(rbx, ltx), 0.0f);
        float h = fmaxf(__fsub_rn(rby, lty), 0.0f);
        float inter = __fmul_rn(w, h);
        float den = __fadd_rn(__fsub_rn(__fadd_rn(ai, aj), inter), 1e-9f);
        if (inter / den > 0.6f) keepw[n * TOPK + gj] = 0;
      }
    }
  }
}

// compact kept (score-sorted) entries via parallel prefix scan (verified R5 kernel)
__global__ void __launch_bounds__(256)
k_final(const uint32_t* __restrict__ keepw, const float* __restrict__ boxw,
        const uint32_t* __restrict__ labw, const float* __restrict__ scw,
        float* __restrict__ out){
  const int n = blockIdx.x;
  __shared__ uint16_t fi_s[TOPK];
  __shared__ uint32_t wsum[4];
  const int t = threadIdx.x;
  const int i0 = t * 4;
  uint32_t f[4];
  #pragma unroll
  for (int j = 0; j < 4; ++j)
    f[j] = (i0 + j < TOPK) ? keepw[n * TOPK + i0 + j] : 0u;
  uint32_t lsum = f[0] + f[1] + f[2] + f[3];
  uint32_t sc = lsum;
  #pragma unroll
  for (int d = 1; d < 64; d <<= 1){
    uint32_t v = __shfl_up(sc, d);
    if ((t & 63) >= d) sc += v;
  }
  if ((t & 63) == 63) wsum[t >> 6] = sc;
  __syncthreads();
  uint32_t base = sc - lsum;
  for (int w = 0; w < (t >> 6); ++w) base += wsum[w];
  uint32_t p = base;
  #pragma unroll
  for (int j = 0; j < 4; ++j){
    if (f[j]){ if (p < TOPK) fi_s[p] = (uint16_t)(i0 + j); ++p; }
  }
  __syncthreads();
  uint32_t total = wsum[0] + wsum[1] + wsum[2] + wsum[3];
  if (t < POSTK){
    float* row = out + ((size_t)n * POSTK + t) * 6;
    if (t < (int)total){
      int i = (int)fi_s[t];
      size_t b4 = ((size_t)n * TOPK + i) * 4;
      row[0] = boxw[b4]; row[1] = boxw[b4 + 1]; row[2] = boxw[b4 + 2]; row[3] = boxw[b4 + 3];
      row[4] = (float)labw[n * TOPK + i]; row[5] = scw[n * TOPK + i];
    } else {
      row[0] = 0.0f; row[1] = 0.0f; row[2] = 0.0f;
      row[3] = 0.0f; row[4] = 0.0f; row[5] = 0.0f;
    }
  }
}

extern "C" void kernel_launch(void* const* d_in, const int* in_sizes, int n_in,
                              void* d_out, int out_size, void* d_ws, size_t ws_size,
                              hipStream_t stream){
  const float* locations = (const float*)d_in[0];
  const float* box_cls   = (const float*)d_in[1];
  const float* box_reg   = (const float*)d_in[2];
  const float* ctr       = (const float*)d_in[3];
  const float* im_info   = (const float*)d_in[4];
  float* out = (float*)d_out;
  char* ws = (char*)d_ws;
  uint32_t* cnt  = (uint32_t*)(ws + B_CNT);
  uint32_t* meta = (uint32_t*)(ws + B_META);
  uint64_t* skey = (uint64_t*)(ws + B_SKEY);
  float*    ctrs = (float*)(ws + B_CTRS);
  uint64_t* cand = (uint64_t*)(ws + B_CAND);
  float*    boxw  = (float*)(ws + B_BOX);
  float*    oboxw = (float*)(ws + B_OBOX);
  float*    scw   = (float*)(ws + B_SC);
  uint32_t* valw  = (uint32_t*)(ws + B_VAL);
  uint32_t* labw  = (uint32_t*)(ws + B_LAB);
  uint32_t* keepw = (uint32_t*)(ws + B_KEEP);

  k_ctrsig<<<dim3(119), 256, 0, stream>>>(ctr, ctrs, cnt, skey);
  k_sample<<<dim3(NIMG), 256, 0, stream>>>(box_cls, ctrs, meta);
  k_main<<<dim3(HBLK, NIMG), 256, 0, stream>>>(box_cls, ctrs, meta, cnt, cand);
  k_fallback<<<dim3(NIMG), 1024, 0, stream>>>(box_cls, ctrs, meta, cnt, cand);
  k_rank<<<dim3(RBLK, NIMG), 256, 0, stream>>>(cnt, cand, skey);
  k_decode<<<NIMG, 1024, 0, stream>>>(skey, locations, box_reg, im_info,
                                      boxw, oboxw, scw, valw, labw);
  k_nms<<<dim3(NCLS, NIMG), 64, 0, stream>>>(labw, oboxw, valw, keepw);
  k_final<<<NIMG, 256, 0, stream>>>(keepw, boxw, labw, scw, out);
}

// Round 9
// 185.066 us; speedup vs baseline: 1.1204x; 1.1204x over previous
//
#include <hip/hip_runtime.h>
#include <stdint.h>

#define NIMG 8
#define NCLS 80
#define HF 100
#define WF 152
#define NPTS (HF*WF)          // 15200
#define NPC (NPTS*NCLS)       // 1216000
#define NF4 (NPC/4)           // 304000 float4 groups per image
#define TOPK 1000
#define NSH 8                 // candidate shards per image
#define SHCAP 512             // slots per shard (expected ~300, cap = +12 sigma)
#define SORTN 4096            // max total candidates = NSH*SHCAP
#define LBUF 1024             // per-block LDS candidate buffer
#define POSTK 100
#define HBLK 297              // ceil(NF4/1024): 256 thr x 4 float4 groups = 4096 elems/block
#define RBLK (SORTN/256)      // 16 rank blocks per image
#define SCHUNK 32             // sample chunks per image
#define SSTRIDE 9500          // groups between chunk starts (32*9500+255 < 304000)
#define SM_T 65               // sample-suffix target: ~65/0.02695 = 2400 expected true count

// ---- workspace layout (bytes) ----
static constexpr size_t B_CNT  = 0;                                    // u32 [8][NSH]
static constexpr size_t B_META = B_CNT + (size_t)NIMG*NSH*4;           // u32 [8][4] {-, T_raw, -, -}
static constexpr size_t B_SKEY = (B_META + NIMG*4*4 + 7) & ~(size_t)7; // u64 [8][1024]
static constexpr size_t B_CTRS = (B_SKEY + (size_t)NIMG*1024*8 + 15) & ~(size_t)15; // f32 [8][15200]
static constexpr size_t B_CAND = (B_CTRS + (size_t)NIMG*NPTS*4 + 15) & ~(size_t)15; // u64 [8][NSH][SHCAP]
static constexpr size_t B_BOX  = B_CAND + (size_t)NIMG*NSH*SHCAP*8;    // f32 [8][TOPK][4]
static constexpr size_t B_OBOX = B_BOX + (size_t)NIMG*TOPK*16;         // f32 [8][TOPK][4]
static constexpr size_t B_SC   = B_OBOX + (size_t)NIMG*TOPK*16;        // f32 [8][TOPK]
static constexpr size_t B_VAL  = B_SC + (size_t)NIMG*TOPK*4;           // u32 [8][TOPK]
static constexpr size_t B_LAB  = B_VAL + (size_t)NIMG*TOPK*4;          // u32 [8][TOPK]
static constexpr size_t B_KEEP = B_LAB + (size_t)NIMG*TOPK*4;          // u32 [8][TOPK]
#define ZWORDS (NIMG*NSH + NIMG*4)   // cnt + meta u32 words (contiguous)

__device__ __forceinline__ float sigm(float x){ return 1.0f / (1.0f + expf(-x)); }

// sigmoid(centerness) precompute + zero cnt/meta/skey (replaces hipMemsetAsync)
__global__ void __launch_bounds__(256)
k_ctrsig(const float* __restrict__ ctr, float* __restrict__ ctr_sig,
         uint32_t* __restrict__ zr, uint64_t* __restrict__ skey){
  const int gid = blockIdx.x * 256 + threadIdx.x;
  const int nthr = 119 * 256;
  if (gid < NIMG*NPTS/4){
    float4 v = ((const float4*)ctr)[gid];
    float4 o;
    o.x = sigm(v.x); o.y = sigm(v.y); o.z = sigm(v.z); o.w = sigm(v.w);
    ((float4*)ctr_sig)[gid] = o;
  }
  for (int i = gid; i < ZWORDS; i += nthr) zr[i] = 0u;           // cnt + meta
  for (int i = gid; i < NIMG*1024; i += nthr) skey[i] = 0ull;    // skey
}

// sample ~2.7% of elements, build 4096-bin hist, pick speculative threshold T_raw:
// largest bin with sample-suffix >= SM_T  =>  expected true count(>=T) ~ 2400.
// T_raw is a PERFORMANCE HINT ONLY: k_fallback guarantees exactness for any T_raw.
__global__ void __launch_bounds__(256)
k_sample(const float* __restrict__ box_cls, const float* __restrict__ ctr_sig,
         uint32_t* __restrict__ meta){
  __shared__ uint32_t h[4096];
  __shared__ uint32_t psum[256], suff[256];
  const int n = blockIdx.x;
  const int t = threadIdx.x;
  for (int i = t; i < 4096; i += 256) h[i] = 0;
  __syncthreads();
  const float4* cls4 = (const float4*)(box_cls + (size_t)n * NPC);
  const float* cs = ctr_sig + (size_t)n * NPTS;
  for (int c0 = 0; c0 < SCHUNK; c0 += 4){
    float4 a[4], b[4];
    #pragma unroll
    for (int k = 0; k < 4; ++k){
      int g = (c0 + k) * SSTRIDE + t;
      a[k] = cls4[g];
      uint32_t p0 = ((uint32_t)(g << 2)) % (uint32_t)NPTS;
      b[k] = *(const float4*)(cs + p0);
    }
    __builtin_amdgcn_sched_barrier(0);
    #pragma unroll
    for (int k = 0; k < 4; ++k){
      float sv[4] = {a[k].x, a[k].y, a[k].z, a[k].w};
      float cv[4] = {b[k].x, b[k].y, b[k].z, b[k].w};
      #pragma unroll
      for (int j = 0; j < 4; ++j){
        float s = sigm(sv[j]);
        if (s > 0.05f){
          float sc = s * cv[j];
          if (sc > 0.0f) atomicAdd(&h[__float_as_uint(sc) >> 18], 1u);
        }
      }
    }
  }
  __syncthreads();
  uint32_t s = 0;
  #pragma unroll
  for (int i = 0; i < 16; ++i) s += h[t * 16 + i];
  psum[t] = s;
  __syncthreads();
  if (t == 0){
    uint32_t acc = 0;
    for (int seg = 255; seg >= 0; --seg){ suff[seg] = acc; acc += psum[seg]; }
  }
  __syncthreads();
  if (suff[t] < SM_T && suff[t] + psum[t] >= SM_T){
    uint32_t acc = suff[t];
    for (int b = t * 16 + 15; b >= t * 16; --b){
      uint32_t hb = h[b];
      if (acc + hb >= SM_T){
        meta[n * 4 + 1] = ((uint32_t)b) << 18;   // raw-bits threshold
        break;
      }
      acc += hb;
    }
  }
}

// THE single full pass: compute scores, collect bits >= T_raw into sharded buffers.
__global__ void __launch_bounds__(256)
k_main(const float* __restrict__ box_cls, const float* __restrict__ ctr_sig,
       const uint32_t* __restrict__ meta,
       uint32_t* __restrict__ cnt, uint64_t* __restrict__ cand){
  __shared__ uint64_t buf[LBUF];
  __shared__ uint32_t lcnt;
  __shared__ uint32_t gbase;
  const int n = blockIdx.y;
  const uint32_t Traw = meta[n * 4 + 1];
  if (threadIdx.x == 0) lcnt = 0;
  __syncthreads();
  const float4* cls4 = (const float4*)(box_cls + (size_t)n * NPC);
  const float* cs = ctr_sig + (size_t)n * NPTS;
  const int base4 = blockIdx.x * 1024 + threadIdx.x;
  float4 a[4], b[4];
  int p0a[4], ca[4];
  bool ok[4];
  #pragma unroll
  for (int k = 0; k < 4; ++k){
    int i4 = base4 + k * 256;
    ok[k] = (i4 < NF4);
    if (ok[k]){
      a[k] = cls4[i4];
      uint32_t e0 = (uint32_t)(i4 << 2);
      uint32_t c = e0 / (uint32_t)NPTS;      // constant within a 4-aligned group
      uint32_t p0 = e0 - c * (uint32_t)NPTS;
      ca[k] = (int)c; p0a[k] = (int)p0;
      b[k] = *(const float4*)(cs + p0);
    }
  }
  __builtin_amdgcn_sched_barrier(0);         // keep all 8 loads issued up-front (MLP)
  #pragma unroll
  for (int k = 0; k < 4; ++k){
    if (!ok[k]) continue;
    float sv[4] = {a[k].x, a[k].y, a[k].z, a[k].w};
    float cv[4] = {b[k].x, b[k].y, b[k].z, b[k].w};
    #pragma unroll
    for (int j = 0; j < 4; ++j){
      float s = sigm(sv[j]);
      if (s > 0.05f){
        float sc = s * cv[j];
        if (sc > 0.0f){
          uint32_t bits = __float_as_uint(sc);
          if (bits >= Traw){
            uint32_t f = (uint32_t)(p0a[k] + j) * NCLS + (uint32_t)ca[k]; // ref flat idx
            uint32_t pos = atomicAdd(&lcnt, 1u);
            if (pos < LBUF)
              buf[pos] = ((uint64_t)bits << 32) | (uint64_t)(0xFFFFFFFFu - f);
          }
        }
      }
    }
  }
  __syncthreads();
  uint32_t c = lcnt; if (c > LBUF) c = LBUF;
  const int sh = blockIdx.x & (NSH - 1);
  if (threadIdx.x == 0 && c) gbase = atomicAdd(&cnt[n * NSH + sh], c);  // 1 atomic/block
  __syncthreads();
  for (uint32_t i = threadIdx.x; i < c; i += 256){
    uint32_t p = gbase + i;
    if (p < SHCAP) cand[(((size_t)n * NSH + sh) << 9) + p] = buf[i];
  }
}

// Exactness guard (always launched; no-op when speculation succeeded).
__global__ void __launch_bounds__(1024)
k_fallback(const float* __restrict__ box_cls, const float* __restrict__ ctr_sig,
           const uint32_t* __restrict__ meta,
           uint32_t* __restrict__ cnt, uint64_t* __restrict__ cand){
  __shared__ uint32_t h[4096];
  __shared__ uint32_t psum[256], suff[256];
  __shared__ uint32_t ok_s, T14_s, ctr_s;
  const int n = blockIdx.x;
  const int t = threadIdx.x;
  if (t == 0){
    uint32_t total = 0, bad = 0;
    for (int s = 0; s < NSH; ++s){
      uint32_t c = cnt[n * NSH + s];
      total += c; bad |= (c > SHCAP) ? 1u : 0u;
    }
    uint32_t Traw = meta[n * 4 + 1];
    ok_s = (!bad && (total >= TOPK || Traw == 0u)) ? 1u : 0u;
    T14_s = 0; ctr_s = 0;
  }
  __syncthreads();
  if (ok_s) return;
  // ---- slow exact path ----
  for (int i = t; i < 4096; i += 1024) h[i] = 0;
  __syncthreads();
  const float* cls = box_cls + (size_t)n * NPC;
  const float* cs = ctr_sig + (size_t)n * NPTS;
  for (int e = t; e < NPC; e += 1024){
    int c = e / NPTS, p = e - c * NPTS;
    float s = sigm(cls[e]);
    if (s > 0.05f){
      float sc = s * cs[p];
      if (sc > 0.0f) atomicAdd(&h[__float_as_uint(sc) >> 18], 1u);
    }
  }
  __syncthreads();
  if (t < 256){
    uint32_t s = 0;
    #pragma unroll
    for (int i = 0; i < 16; ++i) s += h[t * 16 + i];
    psum[t] = s;
  }
  __syncthreads();
  if (t == 0){
    uint32_t acc = 0;
    for (int seg = 255; seg >= 0; --seg){ suff[seg] = acc; acc += psum[seg]; }
  }
  __syncthreads();
  if (t < 256 && suff[t] < TOPK && suff[t] + psum[t] >= TOPK){
    uint32_t acc = suff[t];
    for (int b = t * 16 + 15; b >= t * 16; --b){
      uint32_t hb = h[b];
      if (acc + hb >= TOPK){ T14_s = (uint32_t)b; break; }
      acc += hb;
    }
  }
  __syncthreads();
  const uint32_t Traw2 = T14_s << 18;        // 0 => collect all positive candidates
  if (t < NSH) cnt[n * NSH + t] = 0;
  __syncthreads();
  for (int e = t; e < NPC; e += 1024){
    int c = e / NPTS, p = e - c * NPTS;
    float s = sigm(cls[e]);
    if (s > 0.05f){
      float sc = s * cs[p];
      if (sc > 0.0f){
        uint32_t bits = __float_as_uint(sc);
        if (bits >= Traw2){
          uint32_t f = (uint32_t)p * NCLS + (uint32_t)c;
          uint32_t pos = atomicAdd(&ctr_s, 1u);
          if (pos < SORTN)
            cand[((size_t)n * NSH << 9) + pos] = ((uint64_t)bits << 32) | (uint64_t)(0xFFFFFFFFu - f);
        }
      }
    }
  }
  __syncthreads();
  if (t < NSH){
    uint32_t total = ctr_s; if (total > SORTN) total = SORTN;
    int lo = t * SHCAP;
    cnt[n * NSH + t] = ((int)total > lo) ? ((total - lo > SHCAP) ? SHCAP : total - lo) : 0u;
  }
}

// rank-based selection via REGISTER SHUFFLE: each lane loads a distinct key
// (1 coalesced ds_read_b64 per 64 keys), then v_readlane broadcasts it lane-by-lane.
// Replaces the 2400-deep broadcast-LDS-read latency chain (66us) with a
// VALU-issue-bound compare loop (~38 LDS ops/thread instead of 2400).
__global__ void __launch_bounds__(256)
k_rank(const uint32_t* __restrict__ cnt, const uint64_t* __restrict__ cand,
       uint64_t* __restrict__ skey){
  __shared__ alignas(16) uint64_t keys[SORTN + 64];
  __shared__ uint32_t cs_s[NSH], pre_s[NSH + 1];
  const int n = blockIdx.y;
  const int t = threadIdx.x;
  const int lane = t & 63;
  if (t == 0){
    uint32_t acc = 0;
    for (int s = 0; s < NSH; ++s){
      uint32_t c = cnt[n * NSH + s]; if (c > SHCAP) c = SHCAP;
      cs_s[s] = c; pre_s[s] = acc; acc += c;
    }
    pre_s[NSH] = acc;
  }
  __syncthreads();
  const int total = (int)pre_s[NSH];
  const int base = blockIdx.x * 256;
  if (base >= total) return;                 // block-uniform early exit
  for (int i = t; i < SORTN; i += 256){
    int s = i >> 9, j = i & (SHCAP - 1);
    if ((uint32_t)j < cs_s[s])
      keys[pre_s[s] + j] = cand[(((size_t)n * NSH + s) << 9) + j];
  }
  if (t < 64) keys[total + t] = 0ull;        // zero-pad to the next 64 multiple
  __syncthreads();
  const int g = base + t;
  const uint64_t my = (g < total) ? keys[g] : 0ull;
  uint32_t rank = 0;
  const int tot64 = (total + 63) & ~63;
  for (int i = 0; i < tot64; i += 64){
    uint64_t kv = keys[i + lane];            // coalesced: 2-way bank aliasing (free)
    uint32_t kvlo = (uint32_t)kv, kvhi = (uint32_t)(kv >> 32);
    #pragma unroll
    for (int s = 0; s < 64; ++s){
      uint32_t ohi = (uint32_t)__builtin_amdgcn_readlane((int)kvhi, s);
      uint32_t olo = (uint32_t)__builtin_amdgcn_readlane((int)kvlo, s);
      uint64_t other = ((uint64_t)ohi << 32) | (uint64_t)olo;
      rank += (other > my) ? 1u : 0u;
    }
  }
  if (g < total && rank < TOPK)
    skey[(size_t)n * 1024 + rank] = my;      // ranks in [0,total) are a permutation
}

// decode boxes for the 1000 rank-ordered keys (verified kernel)
__global__ void __launch_bounds__(1024)
k_decode(const uint64_t* __restrict__ skey,
         const float* __restrict__ locations, const float* __restrict__ box_reg,
         const float* __restrict__ im_info,
         float* __restrict__ boxw, float* __restrict__ oboxw, float* __restrict__ scw,
         uint32_t* __restrict__ valw, uint32_t* __restrict__ labw){
  const int n = blockIdx.x;
  const int t = threadIdx.x;
  if (t < TOPK){
    uint64_t kk = skey[(size_t)n * 1024 + t];
    uint32_t bits = (uint32_t)(kk >> 32);
    uint32_t fi = 0xFFFFFFFFu - (uint32_t)(kk & 0xFFFFFFFFull);
    float v = __uint_as_float(bits);
    int loc = 0, ci = 0;
    if (v > 0.0f){ loc = (int)(fi / NCLS); ci = (int)(fi - (uint32_t)loc * NCLS); }
    float px = locations[2 * loc], py = locations[2 * loc + 1];
    const float* rg = box_reg + (size_t)n * 4 * NPTS;
    float rl = rg[loc], rt = rg[NPTS + loc], rr = rg[2 * NPTS + loc], rb = rg[3 * NPTS + loc];
    float h_im = im_info[n * 2 + 0], w_im = im_info[n * 2 + 1];
    float x1 = fminf(fmaxf(px - rl, 0.0f), w_im - 1.0f);
    float y1 = fminf(fmaxf(py - rt, 0.0f), h_im - 1.0f);
    float x2 = fminf(fmaxf(px + rr, 0.0f), w_im - 1.0f);
    float y2 = fminf(fmaxf(py + rb, 0.0f), h_im - 1.0f);
    bool valid = (v > 0.0f) && (__fsub_rn(x2, x1) >= 0.0f) && (__fsub_rn(y2, y1) >= 0.0f);
    float scv = valid ? v : 0.0f;
    float lab = (float)(ci + 1);
    float off = __fmul_rn(lab, 100000.0f);   // CLASS_OFFSET, mul then add (no fma) like ref
    size_t b4 = ((size_t)n * TOPK + t) * 4;
    boxw[b4 + 0] = x1; boxw[b4 + 1] = y1; boxw[b4 + 2] = x2; boxw[b4 + 3] = y2;
    oboxw[b4 + 0] = __fadd_rn(x1, off); oboxw[b4 + 1] = __fadd_rn(y1, off);
    oboxw[b4 + 2] = __fadd_rn(x2, off); oboxw[b4 + 3] = __fadd_rn(y2, off);
    size_t b1 = (size_t)n * TOPK + t;
    scw[b1] = scv; valw[b1] = valid ? 1u : 0u; labw[b1] = (uint32_t)(ci + 1);
  }
}

// greedy NMS per (image,class), ballot-built class list (verified kernel)
__global__ void __launch_bounds__(64)
k_nms(const uint32_t* __restrict__ labw, const float* __restrict__ oboxw,
      const uint32_t* __restrict__ valw, uint32_t* __restrict__ keepw){
  const int n = blockIdx.y;
  const int c = blockIdx.x;                  // 0-based; label = c+1
  const int L = threadIdx.x;
  __shared__ uint16_t lst_s[TOPK];
  const uint32_t target = (uint32_t)(c + 1);
  uint32_t kcnt = 0;
  for (int i0 = 0; i0 < TOPK; i0 += 64){
    int slot = i0 + L;
    uint32_t lab = (slot < TOPK) ? labw[n * TOPK + slot] : 0u;
    bool m = (lab == target);
    uint64_t mask = __ballot(m);
    uint32_t pre = (uint32_t)__popcll(mask & ((1ull << L) - 1ull));
    if (m) lst_s[kcnt + pre] = (uint16_t)slot;
    kcnt += (uint32_t)__popcll(mask);        // uniform across lanes
  }
  __syncthreads();
  if (kcnt == 0) return;
  if (kcnt <= 64){
    int gi = 0, kp = 0;
    float b0 = 0, b1 = 0, b2 = 0, b3 = 0, ar = 0;
    if (L < (int)kcnt){
      gi = (int)lst_s[L];
      size_t a4 = ((size_t)n * TOPK + gi) * 4;
      b0 = oboxw[a4 + 0]; b1 = oboxw[a4 + 1]; b2 = oboxw[a4 + 2]; b3 = oboxw[a4 + 3];
      kp = (valw[n * TOPK + gi] != 0) ? 1 : 0;
      ar = __fmul_rn(fmaxf(__fsub_rn(b2, b0), 0.0f), fmaxf(__fsub_rn(b3, b1), 0.0f));
    }
    for (int i = 0; i + 1 < (int)kcnt; ++i){
      int alive = __shfl(kp, i);
      float xi0 = __shfl(b0, i), xi1 = __shfl(b1, i), xi2 = __shfl(b2, i), xi3 = __shfl(b3, i);
      float ai = __shfl(ar, i);
      if (alive && L > i && kp){
        float ltx = fmaxf(xi0, b0), lty = fmaxf(xi1, b1);
        float rbx = fminf(xi2, b2), rby = fminf(xi3, b3);
        float w = fmaxf(__fsub_rn(rbx, ltx), 0.0f);
        float h = fmaxf(__fsub_rn(rby, lty), 0.0f);
        float inter = __fmul_rn(w, h);
        float den = __fadd_rn(__fsub_rn(__fadd_rn(ai, ar), inter), 1e-9f);
        if (inter / den > 0.6f) kp = 0;
      }
    }
    if (L < (int)kcnt) keepw[n * TOPK + gi] = (uint32_t)kp;
  } else if (L == 0){
    // slow path (kcnt > 64): sequential, correctness-only (statistically never hit)
    for (uint32_t i = 0; i < kcnt; ++i){
      int gi = (int)lst_s[i];
      keepw[n * TOPK + gi] = valw[n * TOPK + gi];
    }
    for (uint32_t i = 0; i < kcnt; ++i){
      int gi = (int)lst_s[i];
      if (!keepw[n * TOPK + gi]) continue;
      size_t a4 = ((size_t)n * TOPK + gi) * 4;
      float x0 = oboxw[a4], x1 = oboxw[a4 + 1], x2 = oboxw[a4 + 2], x3 = oboxw[a4 + 3];
      float ai = __fmul_rn(fmaxf(__fsub_rn(x2, x0), 0.0f), fmaxf(__fsub_rn(x3, x1), 0.0f));
      for (uint32_t j = i + 1; j < kcnt; ++j){
        int gj = (int)lst_s[j];
        if (!keepw[n * TOPK + gj]) continue;
        size_t c4 = ((size_t)n * TOPK + gj) * 4;
        float y0 = oboxw[c4], y1 = oboxw[c4 + 1], y2 = oboxw[c4 + 2], y3 = oboxw[c4 + 3];
        float aj = __fmul_rn(fmaxf(__fsub_rn(y2, y0), 0.0f), fmaxf(__fsub_rn(y3, y1), 0.0f));
        float ltx = fmaxf(x0, y0), lty = fmaxf(x1, y1);
        float rbx = fminf(x2, y2), rby = fminf(x3, y3);
        float w = fmaxf(__fsub_rn(rbx, ltx), 0.0f);
        float h = fmaxf(__fsub_rn(rby, lty), 0.0f);
        float inter = __fmul_rn(w, h);
        float den = __fadd_rn(__fsub_rn(__fadd_rn(ai, aj), inter), 1e-9f);
        if (inter / den > 0.6f) keepw[n * TOPK + gj] = 0;
      }
    }
  }
}

// compact kept (score-sorted) entries via parallel prefix scan (verified kernel)
__global__ void __launch_bounds__(256)
k_final(const uint32_t* __restrict__ keepw, const float* __restrict__ boxw,
        const uint32_t* __restrict__ labw, const float* __restrict__ scw,
        float* __restrict__ out){
  const int n = blockIdx.x;
  __shared__ uint16_t fi_s[TOPK];
  __shared__ uint32_t wsum[4];
  const int t = threadIdx.x;
  const int i0 = t * 4;
  uint32_t f[4];
  #pragma unroll
  for (int j = 0; j < 4; ++j)
    f[j] = (i0 + j < TOPK) ? keepw[n * TOPK + i0 + j] : 0u;
  uint32_t lsum = f[0] + f[1] + f[2] + f[3];
  uint32_t sc = lsum;
  #pragma unroll
  for (int d = 1; d < 64; d <<= 1){
    uint32_t v = __shfl_up(sc, d);
    if ((t & 63) >= d) sc += v;
  }
  if ((t & 63) == 63) wsum[t >> 6] = sc;
  __syncthreads();
  uint32_t base = sc - lsum;
  for (int w = 0; w < (t >> 6); ++w) base += wsum[w];
  uint32_t p = base;
  #pragma unroll
  for (int j = 0; j < 4; ++j){
    if (f[j]){ if (p < TOPK) fi_s[p] = (uint16_t)(i0 + j); ++p; }
  }
  __syncthreads();
  uint32_t total = wsum[0] + wsum[1] + wsum[2] + wsum[3];
  if (t < POSTK){
    float* row = out + ((size_t)n * POSTK + t) * 6;
    if (t < (int)total){
      int i = (int)fi_s[t];
      size_t b4 = ((size_t)n * TOPK + i) * 4;
      row[0] = boxw[b4]; row[1] = boxw[b4 + 1]; row[2] = boxw[b4 + 2]; row[3] = boxw[b4 + 3];
      row[4] = (float)labw[n * TOPK + i]; row[5] = scw[n * TOPK + i];
    } else {
      row[0] = 0.0f; row[1] = 0.0f; row[2] = 0.0f;
      row[3] = 0.0f; row[4] = 0.0f; row[5] = 0.0f;
    }
  }
}

extern "C" void kernel_launch(void* const* d_in, const int* in_sizes, int n_in,
                              void* d_out, int out_size, void* d_ws, size_t ws_size,
                              hipStream_t stream){
  const float* locations = (const float*)d_in[0];
  const float* box_cls   = (const float*)d_in[1];
  const float* box_reg   = (const float*)d_in[2];
  const float* ctr       = (const float*)d_in[3];
  const float* im_info   = (const float*)d_in[4];
  float* out = (float*)d_out;
  char* ws = (char*)d_ws;
  uint32_t* cnt  = (uint32_t*)(ws + B_CNT);
  uint32_t* meta = (uint32_t*)(ws + B_META);
  uint64_t* skey = (uint64_t*)(ws + B_SKEY);
  float*    ctrs = (float*)(ws + B_CTRS);
  uint64_t* cand = (uint64_t*)(ws + B_CAND);
  float*    boxw  = (float*)(ws + B_BOX);
  float*    oboxw = (float*)(ws + B_OBOX);
  float*    scw   = (float*)(ws + B_SC);
  uint32_t* valw  = (uint32_t*)(ws + B_VAL);
  uint32_t* labw  = (uint32_t*)(ws + B_LAB);
  uint32_t* keepw = (uint32_t*)(ws + B_KEEP);

  k_ctrsig<<<dim3(119), 256, 0, stream>>>(ctr, ctrs, cnt, skey);
  k_sample<<<dim3(NIMG), 256, 0, stream>>>(box_cls, ctrs, meta);
  k_main<<<dim3(HBLK, NIMG), 256, 0, stream>>>(box_cls, ctrs, meta, cnt, cand);
  k_fallback<<<dim3(NIMG), 1024, 0, stream>>>(box_cls, ctrs, meta, cnt, cand);
  k_rank<<<dim3(RBLK, NIMG), 256, 0, stream>>>(cnt, cand, skey);
  k_decode<<<NIMG, 1024, 0, stream>>>(skey, locations, box_reg, im_info,
                                      boxw, oboxw, scw, valw, labw);
  k_nms<<<dim3(NCLS, NIMG), 64, 0, stream>>>(labw, oboxw, valw, keepw);
  k_final<<<NIMG, 256, 0, stream>>>(keepw, boxw, labw, scw, out);
}